// Round 14
// baseline (2138.160 us; speedup 1.0000x reference)
//
#include <hip/hip_runtime.h>
#include <hip/hip_fp16.h>

#define N_FM 100000
#define N_TP 4096
#define N_SM 100000
#define HID 128
#define E_QOQ 1000000
#define E_BP 1000000
#define E_CP 500000
#define E_CD 500000
#define E_RB 1000000
#define E_TOT 4000000
#define TR 32

// global edge-id order: qoq | cp | rb | bp | cd
#define EO_CP  1000000
#define EO_RB  1500000
#define EO_BP  2500000
#define EO_CD  3500000

// element space (concatenated): qoq | cp | rb | bp | cd
#define EL_QOQ 0
#define EL_CP  (N_FM)
#define EL_RB  (2 * N_FM)
#define EL_BP  (3 * N_FM)
#define EL_CD  (3 * N_FM + N_TP)
#define NTOT   (3 * N_FM + N_TP + N_SM)

// buckets: qoq 128 elems (shift 7) | cp/rb/cd 256 (shift 8) | bp 32 (shift 5)
#define BB_QOQ 0
#define BB_CP  782
#define BB_RB  1173
#define BB_BP  1564
#define BB_CD  1692
#define NBUCK  2083
#define CHUNK  16384
#define NCHUNK ((E_TOT + CHUNK - 1) / CHUNK)

#define PAIRS_CAP 5784064

__device__ __forceinline__ int bucket_base(int b) {
    if (b < BB_CP) return b * 2048;
    if (b < BB_RB) return 1601536 + (b - BB_CP) * 2048;
    if (b < BB_BP) return 2402304 + (b - BB_RB) * 3584;
    if (b < BB_CD) return 3803648 + (b - BB_BP) * 9216;
    return 4983296 + (b - BB_CD) * 2048;
}

typedef _Float16 h2 __attribute__((ext_vector_type(2)));
typedef _Float16 v8h __attribute__((ext_vector_type(8)));
typedef float v4f __attribute__((ext_vector_type(4)));

union U32H2 { unsigned u; h2 h; };
union U4H8 { uint4 u; v8h h; };

__device__ __forceinline__ unsigned pk2(float a, float b) {
    U32H2 x; x.h = h2{(_Float16)a, (_Float16)b}; return x.u;
}

// ---------------------------------------------------------------- unified pack kernel
#define R1 (N_FM * 32)
#define R2 (R1 + N_SM * 16)
#define R3 (R2 + N_TP * 16)
#define R4 (R3 + 32 * HID)
#define R5 (R4 + 16 * HID)
#define R6 (R5 + 16 * HID)
#define R7 (R6 + 32 * HID)
#define R8 (R7 + 32 * HID)
#define R9 (R8 + 16 * HID)
#define R10 (R9 + 16 * HID)
#define R11 (R10 + 16 * HID)
#define R12 (R11 + HID)

__device__ __forceinline__ void pack_w_elem(const float* W, unsigned* dst, int j) {
    int rr = j >> 7, c = j & 127;
    dst[j] = pk2(W[(2 * rr) * HID + c], W[(2 * rr + 1) * HID + c]);
}

__global__ void pack_all(const float* __restrict__ x_fm, const float* __restrict__ x_sm,
                         const float* __restrict__ pe_table, const float* __restrict__ pvol,
                         const float* __restrict__ qoq_Wl, const float* __restrict__ cp_Wl,
                         const float* __restrict__ rb_Wl, const float* __restrict__ qoq_Wr,
                         const float* __restrict__ cp_Wr, const float* __restrict__ rb_Wr,
                         const float* __restrict__ bp_Wl, const float* __restrict__ bp_Wr,
                         const float* __restrict__ cd_Wl, const float* __restrict__ cd_Wr,
                         const float* __restrict__ qoq_bl, const float* __restrict__ cp_bl,
                         const float* __restrict__ rb_bl,
                         unsigned* __restrict__ x_fm_f, unsigned* __restrict__ x_sm_f,
                         unsigned* __restrict__ pe_f, unsigned* __restrict__ wf_fm,
                         unsigned* __restrict__ wf_tp, unsigned* __restrict__ wf_sm,
                         float* __restrict__ bias_fm) {
    int gid = blockIdx.x * blockDim.x + threadIdx.x;
    if (gid < R1) {
        float2 t = ((const float2*)x_fm)[gid];
        x_fm_f[gid] = pk2(t.x, t.y);
    } else if (gid < R2) {
        int i = gid - R1;
        float2 t = ((const float2*)x_sm)[i];
        x_sm_f[i] = pk2(t.x, t.y);
    } else if (gid < R3) {
        int i = gid - R2;
        float2 t = ((const float2*)pe_table)[i];
        float v = pvol[i >> 4];
        pe_f[i] = pk2(t.x * v, t.y * v);
    } else if (gid < R4) {
        pack_w_elem(qoq_Wl, wf_fm, gid - R3);
    } else if (gid < R5) {
        pack_w_elem(cp_Wl, wf_fm + 32 * HID, gid - R4);
    } else if (gid < R6) {
        pack_w_elem(rb_Wl, wf_fm + 48 * HID, gid - R5);
    } else if (gid < R7) {
        int j = gid - R6;
        int rr = j >> 7, c = j & 127;
        float a0 = qoq_Wr[(2 * rr) * HID + c] + cp_Wr[(2 * rr) * HID + c] + rb_Wr[(2 * rr) * HID + c];
        float a1 = qoq_Wr[(2 * rr + 1) * HID + c] + cp_Wr[(2 * rr + 1) * HID + c] + rb_Wr[(2 * rr + 1) * HID + c];
        wf_fm[64 * HID + j] = pk2(a0, a1);
    } else if (gid < R8) {
        pack_w_elem(bp_Wl, wf_tp, gid - R7);
    } else if (gid < R9) {
        pack_w_elem(bp_Wr, wf_tp + 32 * HID, gid - R8);
    } else if (gid < R10) {
        pack_w_elem(cd_Wl, wf_sm, gid - R9);
    } else if (gid < R11) {
        pack_w_elem(cd_Wr, wf_sm + 16 * HID, gid - R10);
    } else if (gid < R12) {
        int c = gid - R11;
        bias_fm[c] = qoq_bl[c] + cp_bl[c] + rb_bl[c];
    }
}

// ---------------------------------------------------------------- edge decode
struct EdgePtrs {
    const int *qs, *qd, *cs, *cd_, *rs, *rd, *bs, *bd, *ds, *dd;
};

template <bool NEED_SRC>
__device__ __forceinline__ void edge_decode(const EdgePtrs& P, int e, int& bucket, int& dl, int& src) {
    if (e < EO_CP) {
        int d = P.qd[e]; bucket = BB_QOQ + (d >> 7); dl = d & 127;
        if (NEED_SRC) src = P.qs[e];
    } else if (e < EO_RB) {
        int i = e - EO_CP; int d = P.cd_[i]; bucket = BB_CP + (d >> 8); dl = d & 255;
        if (NEED_SRC) src = P.cs[i];
    } else if (e < EO_BP) {
        int i = e - EO_RB; int d = P.rd[i]; bucket = BB_RB + (d >> 8); dl = d & 255;
        if (NEED_SRC) src = P.rs[i];
    } else if (e < EO_CD) {
        int i = e - EO_BP; int d = P.bd[i]; bucket = BB_BP + (d >> 5); dl = d & 31;
        if (NEED_SRC) src = P.bs[i];
    } else {
        int i = e - EO_CD; int d = P.dd[i]; bucket = BB_CD + (d >> 8); dl = d & 255;
        if (NEED_SRC) src = P.ds[i];
    }
}

// ---------------------------------------------------------------- bin: block-reserved bucket scatter
__global__ void __launch_bounds__(256) bin_kernel(EdgePtrs P, int* __restrict__ bwork,
                                                  unsigned* __restrict__ pairs) {
    __shared__ int lh[NBUCK];
    const int tid = threadIdx.x;
    for (int i = tid; i < NBUCK; i += 256) lh[i] = 0;
    __syncthreads();
    int base = blockIdx.x * CHUNK;
    int lim = min(base + CHUNK, E_TOT);
    for (int e = base + tid; e < lim; e += 256) {
        int b, dl, s;
        edge_decode<false>(P, e, b, dl, s);
        atomicAdd(&lh[b], 1);
    }
    __syncthreads();
    for (int b = tid; b < NBUCK; b += 256) {
        int c = lh[b];
        lh[b] = c ? bucket_base(b) + atomicAdd(&bwork[b], c) : 0;
    }
    __syncthreads();
    for (int e = base + tid; e < lim; e += 256) {
        int b, dl, s;
        edge_decode<true>(P, e, b, dl, s);
        int pos = atomicAdd(&lh[b], 1);
        pairs[pos] = ((unsigned)dl << 24) | (unsigned)s;
    }
}

// ---------------------------------------------------------------- esort: per-bucket LDS counting sort by element
__global__ void __launch_bounds__(256) esort(const int* __restrict__ bwork,
                                             const unsigned* __restrict__ pairs,
                                             int* __restrict__ so,
                                             int* __restrict__ el_beg, int* __restrict__ el_end) {
    __shared__ int hist[256], scn[256];
    const int b = blockIdx.x;
    const int tid = threadIdx.x;
    int beg = bucket_base(b);
    int end = beg + bwork[b];
    int egbase, ne;
    if (b < BB_CP)      { int e0 = (b - BB_QOQ) << 7; egbase = EL_QOQ + e0; ne = min(128, N_FM - e0); }
    else if (b < BB_RB) { int e0 = (b - BB_CP) << 8;  egbase = EL_CP + e0;  ne = min(256, N_FM - e0); }
    else if (b < BB_BP) { int e0 = (b - BB_RB) << 8;  egbase = EL_RB + e0;  ne = min(256, N_FM - e0); }
    else if (b < BB_CD) { int e0 = (b - BB_BP) << 5;  egbase = EL_BP + e0;  ne = min(32, N_TP - e0); }
    else                { int e0 = (b - BB_CD) << 8;  egbase = EL_CD + e0;  ne = min(256, N_SM - e0); }
    hist[tid] = 0;
    __syncthreads();
    for (int e = beg + tid; e < end; e += 256)
        atomicAdd(&hist[pairs[e] >> 24], 1);
    __syncthreads();
    int v = hist[tid];
    scn[tid] = v;
    __syncthreads();
    for (int off = 1; off < 256; off <<= 1) {
        int u = (tid >= off) ? scn[tid - off] : 0;
        __syncthreads();
        scn[tid] += u;
        __syncthreads();
    }
    int excl = scn[tid] - v;
    if (tid < ne) {
        el_beg[egbase + tid] = beg + excl;
        el_end[egbase + tid] = beg + excl + v;
    }
    hist[tid] = excl;  // cursor
    __syncthreads();
    for (int e = beg + tid; e < end; e += 256) {
        unsigned pr = pairs[e];
        int dl = pr >> 24;
        int pos = atomicAdd(&hist[dl], 1);
        so[beg + pos] = (int)(pr & 0xFFFFFF);
    }
}

// ---------------------------------------------------------------- gather: element CSR, register fp32 accumulate
template <int LOGP>
__device__ __forceinline__ void gather_one(int g, int lane, const int* __restrict__ begs,
                                           const int* __restrict__ ends,
                                           const int* __restrict__ ssrc,
                                           const unsigned* __restrict__ feat,
                                           unsigned* __restrict__ mean) {
    const int P = 1 << LOGP;
    int beg = begs[g], end = ends[g];
    float alo = 0.0f, ahi = 0.0f;
    int i = beg;
    for (; i + 4 <= end; i += 4) {
        int s0 = ssrc[i], s1 = ssrc[i + 1], s2 = ssrc[i + 2], s3 = ssrc[i + 3];
        unsigned v0 = feat[(size_t)s0 * P + lane];
        unsigned v1 = feat[(size_t)s1 * P + lane];
        unsigned v2 = feat[(size_t)s2 * P + lane];
        unsigned v3 = feat[(size_t)s3 * P + lane];
        U32H2 u;
        u.u = v0; alo += (float)u.h[0]; ahi += (float)u.h[1];
        u.u = v1; alo += (float)u.h[0]; ahi += (float)u.h[1];
        u.u = v2; alo += (float)u.h[0]; ahi += (float)u.h[1];
        u.u = v3; alo += (float)u.h[0]; ahi += (float)u.h[1];
    }
    for (; i < end; i++) {
        unsigned v = feat[(size_t)ssrc[i] * P + lane];
        U32H2 u; u.u = v;
        alo += (float)u.h[0]; ahi += (float)u.h[1];
    }
    float ic = (end > beg) ? 1.0f / (float)(end - beg) : 0.0f;
    mean[(size_t)g * P + lane] = pk2(alo * ic, ahi * ic);
}

#define G1 (N_TP * 32)
#define G2 (G1 + N_FM * 32)
#define G3 (G2 + N_FM * 16)
#define G4 (G3 + N_SM * 16)
#define G5 (G4 + N_FM * 16)

__global__ void gather_all(const int* __restrict__ el_beg, const int* __restrict__ el_end,
                           const int* __restrict__ so_all,
                           const unsigned* __restrict__ x_fm_f, const unsigned* __restrict__ pe_f,
                           unsigned* __restrict__ mean_qoq, unsigned* __restrict__ mean_cp,
                           unsigned* __restrict__ mean_rb, unsigned* __restrict__ mean_bp,
                           unsigned* __restrict__ mean_cd) {
    int gid = blockIdx.x * blockDim.x + threadIdx.x;
    if (gid < G1) {
        gather_one<5>(gid >> 5, gid & 31, el_beg + EL_BP, el_end + EL_BP, so_all, x_fm_f, mean_bp);
    } else if (gid < G2) {
        int i = gid - G1;
        gather_one<5>(i >> 5, i & 31, el_beg + EL_QOQ, el_end + EL_QOQ, so_all, x_fm_f, mean_qoq);
    } else if (gid < G3) {
        int i = gid - G2;
        gather_one<4>(i >> 4, i & 15, el_beg + EL_CP, el_end + EL_CP, so_all, pe_f, mean_cp);
    } else if (gid < G4) {
        int i = gid - G3;
        gather_one<4>(i >> 4, i & 15, el_beg + EL_CD, el_end + EL_CD, so_all, pe_f, mean_cd);
    } else if (gid < G5) {
        int i = gid - G4;
        gather_one<4>(i >> 4, i & 15, el_beg + EL_RB, el_end + EL_RB, so_all, pe_f, mean_rb);
    }
}

// ---------------------------------------------------------------- MFMA row kernel
// Block = 256 threads (4 waves); tile = 32 rows of [K = (W0+W1+W2+W3)*2 f16] x W[K][128].
// Wave w owns cols [w*32, w*32+32) (2 N-tiles of 16). B frags preloaded to registers.
// MFMA f16 16x16x32: A[m=lane&15][k=quad*8+j]; B[k=quad*8+j][n=lane&15];
// C/D: col=lane&15, row=quad*4+reg (verified mapping).
template <int WW, int STRIDE>
__device__ __forceinline__ void stage_src(const unsigned* __restrict__ src, size_t row0, int woff,
                                          int tid, unsigned (*s_in)[STRIDE]) {
    constexpr int C = WW / 4;
    for (int i = tid; i < TR * C; i += 256) {
        int r = i / C, q = i % C;
        *(uint4*)&s_in[r][woff + q * 4] = ((const uint4*)src)[row0 * C + i];
    }
}

template <int W0, int W1, int W2, int W3, bool DIV3>
__global__ void __launch_bounds__(256, 3)
rows_mfma(int ntiles,
          const unsigned* __restrict__ src0, const unsigned* __restrict__ src1,
          const unsigned* __restrict__ src2, const unsigned* __restrict__ src3,
          const unsigned* __restrict__ wf, const float* __restrict__ bias,
          const float* __restrict__ ln_g, const float* __restrict__ ln_b,
          float* __restrict__ colsum) {
    constexpr int KW = W0 + W1 + W2 + W3;  // pair-words per row
    constexpr int KK = KW / 16;            // MFMA K-steps
    constexpr int STR = KW + 4;            // LDS row stride (words) -> 2-way-max bank alias
    const int tid = threadIdx.x;
    const int lane = tid & 63;
    const int w = tid >> 6;
    const int l15 = lane & 15;
    const int quad = lane >> 4;
    __shared__ __align__(16) unsigned s_in[TR][STR];
    __shared__ float s_w[4][TR], s_q[4][TR];
    // B fragments (weights) -> registers, loaded once
    U4H8 bfr[2][KK];
#pragma unroll
    for (int ntl = 0; ntl < 2; ntl++)
#pragma unroll
        for (int kk = 0; kk < KK; kk++) {
            int base = kk * 16 + quad * 4;
            int n = w * 32 + ntl * 16 + l15;
            bfr[ntl][kk].u = make_uint4(wf[(base + 0) * HID + n], wf[(base + 1) * HID + n],
                                        wf[(base + 2) * HID + n], wf[(base + 3) * HID + n]);
        }
    const int c0 = w * 32 + l15, c1 = c0 + 16;
    const float cb0 = bias[c0], cb1 = bias[c1];
    const float g0 = ln_g[c0], b0 = ln_b[c0];
    const float g1 = ln_g[c1], b1 = ln_b[c1];
    float colacc0 = 0.0f, colacc1 = 0.0f;
    for (int tile = blockIdx.x; tile < ntiles; tile += gridDim.x) {
        const size_t row0 = (size_t)tile * TR;
        stage_src<W0, STR>(src0, row0, 0, tid, s_in);
        stage_src<W1, STR>(src1, row0, W0, tid, s_in);
        if constexpr (W2 > 0) stage_src<W2, STR>(src2, row0, W0 + W1, tid, s_in);
        if constexpr (W3 > 0) stage_src<W3, STR>(src3, row0, W0 + W1 + W2, tid, s_in);
        __syncthreads();
        v4f acc[2][2];
#pragma unroll
        for (int mt = 0; mt < 2; mt++)
#pragma unroll
            for (int ntl = 0; ntl < 2; ntl++) acc[mt][ntl] = v4f{0.f, 0.f, 0.f, 0.f};
#pragma unroll
        for (int kk = 0; kk < KK; kk++) {
            U4H8 a0, a1;
            a0.u = *(const uint4*)&s_in[l15][kk * 16 + quad * 4];
            a1.u = *(const uint4*)&s_in[16 + l15][kk * 16 + quad * 4];
            acc[0][0] = __builtin_amdgcn_mfma_f32_16x16x32_f16(a0.h, bfr[0][kk].h, acc[0][0], 0, 0, 0);
            acc[0][1] = __builtin_amdgcn_mfma_f32_16x16x32_f16(a0.h, bfr[1][kk].h, acc[0][1], 0, 0, 0);
            acc[1][0] = __builtin_amdgcn_mfma_f32_16x16x32_f16(a1.h, bfr[0][kk].h, acc[1][0], 0, 0, 0);
            acc[1][1] = __builtin_amdgcn_mfma_f32_16x16x32_f16(a1.h, bfr[1][kk].h, acc[1][1], 0, 0, 0);
        }
        // epilogue: bias (+/3), LN across 128 cols, relu, colsum
        float y[2][2][4];
        float sp[2][4], qp[2][4];
#pragma unroll
        for (int mt = 0; mt < 2; mt++)
#pragma unroll
            for (int r = 0; r < 4; r++) {
                float y0 = acc[mt][0][r] + cb0;
                float y1 = acc[mt][1][r] + cb1;
                if (DIV3) { y0 *= (1.0f / 3.0f); y1 *= (1.0f / 3.0f); }
                y[mt][0][r] = y0; y[mt][1][r] = y1;
                float s = y0 + y1, q = y0 * y0 + y1 * y1;
#pragma unroll
                for (int off = 1; off < 16; off <<= 1) {
                    s += __shfl_xor(s, off);
                    q += __shfl_xor(q, off);
                }
                sp[mt][r] = s; qp[mt][r] = q;
            }
        if (l15 == 0) {
#pragma unroll
            for (int mt = 0; mt < 2; mt++)
#pragma unroll
                for (int r = 0; r < 4; r++) {
                    int row = mt * 16 + quad * 4 + r;
                    s_w[w][row] = sp[mt][r];
                    s_q[w][row] = qp[mt][r];
                }
        }
        __syncthreads();
#pragma unroll
        for (int mt = 0; mt < 2; mt++)
#pragma unroll
            for (int r = 0; r < 4; r++) {
                int row = mt * 16 + quad * 4 + r;
                float st = s_w[0][row] + s_w[1][row] + s_w[2][row] + s_w[3][row];
                float qt = s_q[0][row] + s_q[1][row] + s_q[2][row] + s_q[3][row];
                float mu = st * (1.0f / 128.0f);
                float var = fmaxf(qt * (1.0f / 128.0f) - mu * mu, 0.0f);
                float rs = rsqrtf(var + 1e-5f);
                colacc0 += fmaxf((y[mt][0][r] - mu) * rs * g0 + b0, 0.0f);
                colacc1 += fmaxf((y[mt][1][r] - mu) * rs * g1 + b1, 0.0f);
            }
        __syncthreads();
    }
    unsafeAtomicAdd(&colsum[c0], colacc0);
    unsafeAtomicAdd(&colsum[c1], colacc1);
}

// ---------------------------------------------------------------- head MLP -> scalar (split-K)
__global__ void head_kernel(const float* __restrict__ colsum, const float* __restrict__ gf,
                            const float* __restrict__ W1, const float* __restrict__ b1,
                            const float* __restrict__ W2, const float* __restrict__ b2,
                            float* __restrict__ out) {
    __shared__ float h[448];
    __shared__ float sh[512];
    __shared__ float h1[64];
    int t = threadIdx.x;  // 512 threads
    if (t < 128) h[t] = colsum[t] * (1.0f / N_FM);
    else if (t < 256) h[t] = colsum[t] * (1.0f / N_TP);
    else if (t < 384) h[t] = colsum[t] * (1.0f / N_SM);
    else if (t < 448) h[t] = gf[t - 384];
    __syncthreads();
    {
        int col = t & 63, slice = t >> 6;
        float a = 0.0f;
        for (int k = slice * 56; k < slice * 56 + 56; k++) a += h[k] * W1[k * 64 + col];
        sh[slice * 64 + col] = a;
    }
    __syncthreads();
    if (t < 64) {
        float a = b1[t];
#pragma unroll
        for (int s = 0; s < 8; s++) a += sh[s * 64 + t];
        h1[t] = fmaxf(a, 0.0f);
    }
    __syncthreads();
    if (t < 64) {
        float p = h1[t] * W2[t];
#pragma unroll
        for (int off = 1; off < 64; off <<= 1) p += __shfl_xor(p, off);
        if (t == 0) out[0] = p + b2[0];
    }
}

extern "C" void kernel_launch(void* const* d_in, const int* in_sizes, int n_in,
                              void* d_out, int out_size, void* d_ws, size_t ws_size,
                              hipStream_t stream) {
    const float* x_fm = (const float*)d_in[0];
    const float* x_sm = (const float*)d_in[1];
    const float* period_vol = (const float*)d_in[2];
    const float* gf = (const float*)d_in[3];
    const float* pe_table = (const float*)d_in[4];
    const int* qoq_src = (const int*)d_in[5];
    const int* qoq_dst = (const int*)d_in[6];
    const int* bp_src = (const int*)d_in[7];
    const int* bp_dst = (const int*)d_in[8];
    const int* cp_src = (const int*)d_in[9];
    const int* cp_dst = (const int*)d_in[10];
    const int* cd_src = (const int*)d_in[11];
    const int* cd_dst = (const int*)d_in[12];
    const int* rb_src = (const int*)d_in[13];
    const int* rb_dst = (const int*)d_in[14];
    const float* qoq_Wl = (const float*)d_in[15];
    const float* qoq_bl = (const float*)d_in[16];
    const float* qoq_Wr = (const float*)d_in[17];
    const float* bp_Wl = (const float*)d_in[18];
    const float* bp_bl = (const float*)d_in[19];
    const float* bp_Wr = (const float*)d_in[20];
    const float* cp_Wl = (const float*)d_in[21];
    const float* cp_bl = (const float*)d_in[22];
    const float* cp_Wr = (const float*)d_in[23];
    const float* cd_Wl = (const float*)d_in[24];
    const float* cd_bl = (const float*)d_in[25];
    const float* cd_Wr = (const float*)d_in[26];
    const float* rb_Wl = (const float*)d_in[27];
    const float* rb_bl = (const float*)d_in[28];
    const float* rb_Wr = (const float*)d_in[29];
    const float* ln_fm_g = (const float*)d_in[30];
    const float* ln_fm_b = (const float*)d_in[31];
    const float* ln_tp_g = (const float*)d_in[32];
    const float* ln_tp_b = (const float*)d_in[33];
    const float* ln_sm_g = (const float*)d_in[34];
    const float* ln_sm_b = (const float*)d_in[35];
    const float* head_W1 = (const float*)d_in[36];
    const float* head_b1 = (const float*)d_in[37];
    const float* head_W2 = (const float*)d_in[38];
    const float* head_b2 = (const float*)d_in[39];

    // workspace (4-byte words); zero region: bucket cursors + colsum
    unsigned* wsu = (unsigned*)d_ws;
    size_t off = 0;
    int* bwork = (int*)(wsu + off); off += NBUCK;
    float* colsum = (float*)(wsu + off); off += 384;
    size_t zero_words = off;
    unsigned* pairs = wsu + off; off += PAIRS_CAP;
    int* so_all = (int*)(wsu + off); off += PAIRS_CAP;
    int* el_beg = (int*)(wsu + off); off += NTOT;
    int* el_end = (int*)(wsu + off); off += NTOT;
    unsigned* mean_qoq = wsu + off; off += (size_t)N_FM * 32;
    unsigned* mean_cp  = wsu + off; off += (size_t)N_FM * 16;
    unsigned* mean_rb  = wsu + off; off += (size_t)N_FM * 16;
    unsigned* mean_bp  = wsu + off; off += (size_t)N_TP * 32;
    unsigned* mean_cd  = wsu + off; off += (size_t)N_SM * 16;
    unsigned* pe_f     = wsu + off; off += (size_t)N_TP * 16;
    unsigned* x_fm_f   = wsu + off; off += (size_t)N_FM * 32;
    unsigned* x_sm_f   = wsu + off; off += (size_t)N_SM * 16;
    unsigned* wf_fm    = wsu + off; off += 96 * HID;
    unsigned* wf_tp    = wsu + off; off += 48 * HID;
    unsigned* wf_sm    = wsu + off; off += 32 * HID;
    float* bias_fm     = (float*)(wsu + off); off += HID;

    hipMemsetAsync(d_ws, 0, zero_words * 4, stream);

    pack_all<<<(R12 + 255) / 256, 256, 0, stream>>>(
        x_fm, x_sm, pe_table, period_vol, qoq_Wl, cp_Wl, rb_Wl, qoq_Wr, cp_Wr, rb_Wr,
        bp_Wl, bp_Wr, cd_Wl, cd_Wr, qoq_bl, cp_bl, rb_bl,
        x_fm_f, x_sm_f, pe_f, wf_fm, wf_tp, wf_sm, bias_fm);

    EdgePtrs EP{qoq_src, qoq_dst, cp_src, cp_dst, rb_src, rb_dst, bp_src, bp_dst, cd_src, cd_dst};

    bin_kernel<<<NCHUNK, 256, 0, stream>>>(EP, bwork, pairs);
    esort<<<NBUCK, 256, 0, stream>>>(bwork, pairs, so_all, el_beg, el_end);
    gather_all<<<(G5 + 255) / 256, 256, 0, stream>>>(el_beg, el_end, so_all, x_fm_f, pe_f,
                                                     mean_qoq, mean_cp, mean_rb, mean_bp, mean_cd);

    // MFMA row kernels: fm K=192 f16 (96 words), tp K=96 (48), sm K=64 (32)
    rows_mfma<32, 16, 16, 32, true><<<2048, 256, 0, stream>>>(
        N_FM / TR, mean_qoq, mean_cp, mean_rb, x_fm_f, wf_fm, bias_fm,
        ln_fm_g, ln_fm_b, colsum);
    rows_mfma<32, 16, 0, 0, false><<<N_TP / TR, 256, 0, stream>>>(
        N_TP / TR, mean_bp, pe_f, pe_f, pe_f, wf_tp, bp_bl,
        ln_tp_g, ln_tp_b, colsum + 128);
    rows_mfma<16, 16, 0, 0, false><<<2048, 256, 0, stream>>>(
        N_SM / TR, mean_cd, x_sm_f, x_sm_f, x_sm_f, wf_sm, cd_bl,
        ln_sm_g, ln_sm_b, colsum + 256);

    head_kernel<<<1, 512, 0, stream>>>(colsum, gf, head_W1, head_b1, head_W2, head_b2,
                                       (float*)d_out);
}